// Round 1
// baseline (2576.727 us; speedup 1.0000x reference)
//
#include <hip/hip_runtime.h>

#define S_LEN 1024
#define D_DIM 4096
#define FF_DIM 14336
#define KVD 1024
#define NH 32
#define NKVH 8
#define HD 128
#define RANK 16

typedef __bf16 bf16x8 __attribute__((ext_vector_type(8)));
typedef float floatx4 __attribute__((ext_vector_type(4)));

__device__ __forceinline__ unsigned int f2bf(float f) {
  unsigned int u = __builtin_bit_cast(unsigned int, f);
  return (u + 0x7FFFu + ((u >> 16) & 1u)) >> 16;  // RNE
}
__device__ __forceinline__ float bf2f(unsigned int u) {
  return __builtin_bit_cast(float, u << 16);
}

// ---------------------------------------------------------------------------
// Generic batched GEMM: C[z] = alpha * A[z] @ B[z/bDiv]^T
// A bf16 [M,K] row-major, B fp32 [N,K] row-major (converted to bf16 in staging),
// C = OUT_T, row stride ldc, batch offset strideC. M%128==0, N%128==0, K%32==0.
// ---------------------------------------------------------------------------
template <typename OUT_T>
__global__ __launch_bounds__(256, 2) void gemm_bt(
    const unsigned short* __restrict__ A, const float* __restrict__ B,
    OUT_T* __restrict__ C, int M, int N, int K,
    long long strideA, long long strideB, int bDiv,
    long long strideC, int ldc, float alpha) {
  constexpr int LS = 40;  // LDS row stride in bf16 elems (32 + 8 pad)
  __shared__ unsigned short As[128 * LS];
  __shared__ unsigned short Bs[128 * LS];

  const int z = blockIdx.z;
  A += (long long)z * strideA;
  B += (long long)(z / bDiv) * strideB;
  C += (long long)z * strideC;

  const int m0 = blockIdx.y * 128;
  const int n0 = blockIdx.x * 128;
  const int tid = threadIdx.x;
  const int lane = tid & 63;
  const int wave = tid >> 6;
  const int wm = (wave >> 1) << 6;
  const int wn = (wave & 1) << 6;
  const int lrow = lane & 15;
  const int quad = lane >> 4;

  floatx4 acc[4][4];
#pragma unroll
  for (int i = 0; i < 4; ++i)
#pragma unroll
    for (int j = 0; j < 4; ++j) acc[i][j] = (floatx4){0.f, 0.f, 0.f, 0.f};

  const int ar = tid >> 2;            // 0..63
  const int ac = (tid & 3) << 3;      // 0,8,16,24

  for (int ks = 0; ks < K; ks += 32) {
#pragma unroll
    for (int i = 0; i < 2; ++i) {
      const int r = ar + i * 64;
      const uint4 va = *reinterpret_cast<const uint4*>(A + (long long)(m0 + r) * K + ks + ac);
      *reinterpret_cast<uint4*>(&As[r * LS + ac]) = va;
    }
#pragma unroll
    for (int i = 0; i < 2; ++i) {
      const int r = ar + i * 64;
      const float* bp = B + (long long)(n0 + r) * K + ks + ac;
      const float4 f0 = *reinterpret_cast<const float4*>(bp);
      const float4 f1 = *reinterpret_cast<const float4*>(bp + 4);
      uint4 pk;
      pk.x = f2bf(f0.x) | (f2bf(f0.y) << 16);
      pk.y = f2bf(f0.z) | (f2bf(f0.w) << 16);
      pk.z = f2bf(f1.x) | (f2bf(f1.y) << 16);
      pk.w = f2bf(f1.z) | (f2bf(f1.w) << 16);
      *reinterpret_cast<uint4*>(&Bs[r * LS + ac]) = pk;
    }
    __syncthreads();
    bf16x8 af[4], bfr[4];
#pragma unroll
    for (int i = 0; i < 4; ++i)
      af[i] = *reinterpret_cast<const bf16x8*>(&As[(wm + i * 16 + lrow) * LS + quad * 8]);
#pragma unroll
    for (int j = 0; j < 4; ++j)
      bfr[j] = *reinterpret_cast<const bf16x8*>(&Bs[(wn + j * 16 + lrow) * LS + quad * 8]);
#pragma unroll
    for (int i = 0; i < 4; ++i)
#pragma unroll
      for (int j = 0; j < 4; ++j)
        acc[i][j] = __builtin_amdgcn_mfma_f32_16x16x32_bf16(af[i], bfr[j], acc[i][j], 0, 0, 0);
    __syncthreads();
  }

  // C/D layout: col = lane&15, row = quad*4 + reg  (m89-verified)
#pragma unroll
  for (int i = 0; i < 4; ++i) {
#pragma unroll
    for (int j = 0; j < 4; ++j) {
#pragma unroll
      for (int reg = 0; reg < 4; ++reg) {
        const int gr = m0 + wm + i * 16 + quad * 4 + reg;
        const int gc = n0 + wn + j * 16 + lrow;
        const float v = acc[i][j][reg] * alpha;
        if constexpr (sizeof(OUT_T) == 4) {
          C[(long long)gr * ldc + gc] = v;
        } else {
          C[(long long)gr * ldc + gc] = (unsigned short)f2bf(v);
        }
      }
    }
  }
}

// ---------------------------------------------------------------------------
__global__ __launch_bounds__(256) void rmsnorm_kernel(
    const float* __restrict__ x, const float* __restrict__ w,
    unsigned short* __restrict__ out, int D) {
  const long long base = (long long)blockIdx.x * D;
  const int tid = threadIdx.x;
  float ss = 0.f;
  for (int j = tid * 4; j < D; j += 1024) {
    const float4 v = *reinterpret_cast<const float4*>(x + base + j);
    ss += v.x * v.x + v.y * v.y + v.z * v.z + v.w * v.w;
  }
  for (int off = 32; off; off >>= 1) ss += __shfl_down(ss, off);
  __shared__ float red[4];
  if ((tid & 63) == 0) red[tid >> 6] = ss;
  __syncthreads();
  const float total = red[0] + red[1] + red[2] + red[3];
  const float r = rsqrtf(total / (float)D + 1e-5f);
  for (int j = tid * 4; j < D; j += 1024) {
    const float4 v = *reinterpret_cast<const float4*>(x + base + j);
    const float4 wv = *reinterpret_cast<const float4*>(w + j);
    ushort4 o;
    o.x = (unsigned short)f2bf(v.x * r * wv.x);
    o.y = (unsigned short)f2bf(v.y * r * wv.y);
    o.z = (unsigned short)f2bf(v.z * r * wv.z);
    o.w = (unsigned short)f2bf(v.w * r * wv.w);
    *reinterpret_cast<ushort4*>(out + base + j) = o;
  }
}

// t[M,16] = X_bf16[M,K] @ Aw[16,K]^T   (one block per row)
__global__ __launch_bounds__(256) void lora_t_kernel(
    const unsigned short* __restrict__ X, const float* __restrict__ Aw,
    float* __restrict__ t, int K) {
  const int row = blockIdx.x;
  const int tid = threadIdx.x;
  float acc[RANK];
#pragma unroll
  for (int r = 0; r < RANK; ++r) acc[r] = 0.f;
  const unsigned short* xr = X + (long long)row * K;
  for (int k = tid; k < K; k += 256) {
    const float xv = bf2f(xr[k]);
#pragma unroll
    for (int r = 0; r < RANK; ++r) acc[r] += xv * Aw[(long long)r * K + k];
  }
#pragma unroll
  for (int r = 0; r < RANK; ++r)
    for (int off = 32; off; off >>= 1) acc[r] += __shfl_down(acc[r], off);
  __shared__ float red[4][RANK];
  const int lane = tid & 63, wave = tid >> 6;
  if (lane == 0) {
#pragma unroll
    for (int r = 0; r < RANK; ++r) red[wave][r] = acc[r];
  }
  __syncthreads();
  if (tid < RANK)
    t[row * RANK + tid] = red[0][tid] + red[1][tid] + red[2][tid] + red[3][tid];
}

// out = Cin + scale * t@Bw^T (+ res)
__global__ void rank_update_kernel(
    const float* Cin, float* out, const float* __restrict__ t,
    const float* __restrict__ Bw, const float* res, float scale,
    long long total, int N) {
  const long long idx = (long long)blockIdx.x * 256 + threadIdx.x;
  if (idx >= total) return;
  const int n = (int)(idx % N);
  const long long m = idx / N;
  const float* tr = t + m * RANK;
  const float* br = Bw + (long long)n * RANK;
  float s = 0.f;
#pragma unroll
  for (int r = 0; r < RANK; ++r) s += tr[r] * br[r];
  float v = Cin[idx] + scale * s;
  if (res) v += res[idx];
  out[idx] = v;
}

__global__ void rope_q_kernel(const float* __restrict__ xq,
                              const float* __restrict__ cb,
                              const float* __restrict__ sb,
                              unsigned short* __restrict__ q_t) {
  const int idx = blockIdx.x * 256 + threadIdx.x;  // S*NH*64
  const int d2 = idx & 63;
  const int h = (idx >> 6) & 31;
  const int s = idx >> 11;
  const float2 x = reinterpret_cast<const float2*>(xq)[(s * NH + h) * 64 + d2];
  const float c = cb[s * 64 + d2], sn = sb[s * 64 + d2];
  const float o1 = x.x * c - x.y * sn;
  const float o2 = x.x * sn + x.y * c;
  reinterpret_cast<unsigned int*>(q_t)[(h * S_LEN + s) * 64 + d2] =
      f2bf(o1) | (f2bf(o2) << 16);
}

__global__ void rope_k_kernel(const float* __restrict__ xk,
                              const float* __restrict__ cb,
                              const float* __restrict__ sb,
                              float* __restrict__ k_t) {
  const int idx = blockIdx.x * 256 + threadIdx.x;  // S*NKVH*64
  const int d2 = idx & 63;
  const int h = (idx >> 6) & 7;
  const int s = idx >> 9;
  const float2 x = reinterpret_cast<const float2*>(xk)[(s * NKVH + h) * 64 + d2];
  const float c = cb[s * 64 + d2], sn = sb[s * 64 + d2];
  float2 o;
  o.x = x.x * c - x.y * sn;
  o.y = x.x * sn + x.y * c;
  reinterpret_cast<float2*>(k_t)[(h * S_LEN + s) * 64 + d2] = o;
}

__global__ void transpose_v_kernel(const float* __restrict__ xv,
                                   float* __restrict__ v_t) {
  const int idx = blockIdx.x * 256 + threadIdx.x;  // NKVH*HD*S
  const int s = idx & 1023;
  const int d = (idx >> 10) & 127;
  const int h = idx >> 17;
  v_t[((long long)h * HD + d) * S_LEN + s] = xv[((long long)s * NKVH + h) * HD + d];
}

// in-place causal softmax over bf16 score rows; blockIdx.x = head*S + row
__global__ __launch_bounds__(256) void softmax_kernel(unsigned short* probs) {
  const int row = blockIdx.x & (S_LEN - 1);
  unsigned short* p = probs + (long long)blockIdx.x * S_LEN;
  const int tid = threadIdx.x;
  const int n = row + 1;
  float v[4];
  float lmax = -3e38f;
#pragma unroll
  for (int i = 0; i < 4; ++i) {
    const int j = tid + i * 256;
    if (j < n) {
      v[i] = bf2f(p[j]);
      lmax = fmaxf(lmax, v[i]);
    }
  }
  for (int off = 32; off; off >>= 1) lmax = fmaxf(lmax, __shfl_down(lmax, off));
  __shared__ float red[8];
  const int lane = tid & 63, wave = tid >> 6;
  if (lane == 0) red[wave] = lmax;
  __syncthreads();
  const float gmax = fmaxf(fmaxf(red[0], red[1]), fmaxf(red[2], red[3]));
  float lsum = 0.f;
#pragma unroll
  for (int i = 0; i < 4; ++i) {
    const int j = tid + i * 256;
    if (j < n) {
      v[i] = __expf(v[i] - gmax);
      lsum += v[i];
    }
  }
  for (int off = 32; off; off >>= 1) lsum += __shfl_down(lsum, off);
  if (lane == 0) red[4 + wave] = lsum;
  __syncthreads();
  const float inv = 1.f / (red[4] + red[5] + red[6] + red[7]);
#pragma unroll
  for (int i = 0; i < 4; ++i) {
    const int j = tid + i * 256;
    if (j < n)
      p[j] = (unsigned short)f2bf(v[i] * inv);
    else
      p[j] = 0;
  }
}

__global__ void silu_mul_kernel(const float* __restrict__ gate,
                                const float* __restrict__ up,
                                unsigned short* __restrict__ outbf,
                                long long total4) {
  const long long idx = (long long)blockIdx.x * 256 + threadIdx.x;
  if (idx >= total4) return;
  const float4 g = reinterpret_cast<const float4*>(gate)[idx];
  const float4 u = reinterpret_cast<const float4*>(up)[idx];
  ushort4 o;
  o.x = (unsigned short)f2bf(g.x / (1.f + __expf(-g.x)) * u.x);
  o.y = (unsigned short)f2bf(g.y / (1.f + __expf(-g.y)) * u.y);
  o.z = (unsigned short)f2bf(g.z / (1.f + __expf(-g.z)) * u.z);
  o.w = (unsigned short)f2bf(g.w / (1.f + __expf(-g.w)) * u.w);
  reinterpret_cast<ushort4*>(outbf)[idx] = o;
}

// ---------------------------------------------------------------------------
// Workspace layout (bytes) — ~193 MB with reuse
// ---------------------------------------------------------------------------
#define OFF_HBF    0LL              // bf16 [S,D] 8 MB   (f_bf reuses)
#define OFF_TQ     8388608LL
#define OFF_TK     8454144LL
#define OFF_TV     8519680LL
#define OFF_TO     8585216LL
#define OFF_T1     8650752LL
#define OFF_T3     8716288LL
#define OFF_T2     8781824LL
#define OFF_XQ     8847360LL        // f32 [S,D] 16.7 MB (attn_out, gu_bf reuse)
#define OFF_XK     25624576LL       // f32 [S,KVD]
#define OFF_XV     29818880LL       // f32 [S,KVD]
#define OFF_QT     34013184LL       // bf16 [NH,S,HD]
#define OFF_KT     42401792LL       // f32 [NKVH,S,HD]
#define OFF_VT     46596096LL       // f32 [NKVH,HD,S]
#define OFF_PROBS  50790400LL       // bf16 [NH,S,S] 67 MB (up reuses)
#define OFF_ATTNBF 117899264LL      // bf16 [S,D]
#define OFF_DATA2  126287872LL      // f32 [S,D]
#define OFF_GATE   143065088LL      // f32 [S,FF] 58.7 MB (ffn reuses)

extern "C" void kernel_launch(void* const* d_in, const int* in_sizes, int n_in,
                              void* d_out, int out_size, void* d_ws, size_t ws_size,
                              hipStream_t stream) {
  const float* data = (const float*)d_in[0];
  const float* cosb = (const float*)d_in[2];
  const float* sinb = (const float*)d_in[3];
  const float* attn_norm_w = (const float*)d_in[4];
  const float* wq = (const float*)d_in[5];
  const float* wk = (const float*)d_in[6];
  const float* wv = (const float*)d_in[7];
  const float* wo = (const float*)d_in[8];
  const float* wq_a = (const float*)d_in[9];
  const float* wq_b = (const float*)d_in[10];
  const float* wk_a = (const float*)d_in[11];
  const float* wk_b = (const float*)d_in[12];
  const float* wv_a = (const float*)d_in[13];
  const float* wv_b = (const float*)d_in[14];
  const float* wo_a = (const float*)d_in[15];
  const float* wo_b = (const float*)d_in[16];
  const float* ffn_norm_w = (const float*)d_in[17];
  const float* w1 = (const float*)d_in[18];
  const float* w2 = (const float*)d_in[19];
  const float* w3 = (const float*)d_in[20];
  const float* w1_a = (const float*)d_in[21];
  const float* w1_b = (const float*)d_in[22];
  const float* w2_a = (const float*)d_in[23];
  const float* w2_b = (const float*)d_in[24];
  const float* w3_a = (const float*)d_in[25];
  const float* w3_b = (const float*)d_in[26];
  float* out = (float*)d_out;

  char* ws = (char*)d_ws;
  unsigned short* h_bf = (unsigned short*)(ws + OFF_HBF);
  unsigned short* f_bf = h_bf;
  float* t_q = (float*)(ws + OFF_TQ);
  float* t_k = (float*)(ws + OFF_TK);
  float* t_v = (float*)(ws + OFF_TV);
  float* t_o = (float*)(ws + OFF_TO);
  float* t_1 = (float*)(ws + OFF_T1);
  float* t_3 = (float*)(ws + OFF_T3);
  float* t_2 = (float*)(ws + OFF_T2);
  float* xq = (float*)(ws + OFF_XQ);
  float* xk = (float*)(ws + OFF_XK);
  float* xv = (float*)(ws + OFF_XV);
  unsigned short* q_t = (unsigned short*)(ws + OFF_QT);
  float* k_t = (float*)(ws + OFF_KT);
  float* v_t = (float*)(ws + OFF_VT);
  unsigned short* probs = (unsigned short*)(ws + OFF_PROBS);
  unsigned short* attn_bf = (unsigned short*)(ws + OFF_ATTNBF);
  float* attn_out = xq;                       // reuse
  float* data2 = (float*)(ws + OFF_DATA2);
  float* gate = (float*)(ws + OFF_GATE);
  float* up = (float*)(ws + OFF_PROBS);       // reuse (probs dead after PV)
  unsigned short* gu_bf = (unsigned short*)(ws + OFF_XQ);  // reuse
  float* ffn = gate;                          // reuse (gate dead after silu)

  const dim3 blk(256);
  const float inv_sqrt_hd = 0.08838834764831845f;

  // ---- attention pre-norm + QKV + LoRA ----
  rmsnorm_kernel<<<S_LEN, blk, 0, stream>>>(data, attn_norm_w, h_bf, D_DIM);
  lora_t_kernel<<<S_LEN, blk, 0, stream>>>(h_bf, wq_a, t_q, D_DIM);
  lora_t_kernel<<<S_LEN, blk, 0, stream>>>(h_bf, wk_a, t_k, D_DIM);
  lora_t_kernel<<<S_LEN, blk, 0, stream>>>(h_bf, wv_a, t_v, D_DIM);
  gemm_bt<float><<<dim3(32, 8, 1), blk, 0, stream>>>(h_bf, wq, xq, S_LEN, D_DIM, D_DIM, 0, 0, 1, 0, D_DIM, 1.f);
  gemm_bt<float><<<dim3(8, 8, 1), blk, 0, stream>>>(h_bf, wk, xk, S_LEN, KVD, D_DIM, 0, 0, 1, 0, KVD, 1.f);
  gemm_bt<float><<<dim3(8, 8, 1), blk, 0, stream>>>(h_bf, wv, xv, S_LEN, KVD, D_DIM, 0, 0, 1, 0, KVD, 1.f);
  rank_update_kernel<<<(S_LEN * D_DIM) / 256, blk, 0, stream>>>(xq, xq, t_q, wq_b, nullptr, 2.f, (long long)S_LEN * D_DIM, D_DIM);
  rank_update_kernel<<<(S_LEN * KVD) / 256, blk, 0, stream>>>(xk, xk, t_k, wk_b, nullptr, 2.f, (long long)S_LEN * KVD, KVD);
  rank_update_kernel<<<(S_LEN * KVD) / 256, blk, 0, stream>>>(xv, xv, t_v, wv_b, nullptr, 2.f, (long long)S_LEN * KVD, KVD);

  // ---- RoPE + layout transforms ----
  rope_q_kernel<<<(S_LEN * NH * 64) / 256, blk, 0, stream>>>(xq, cosb, sinb, q_t);
  rope_k_kernel<<<(S_LEN * NKVH * 64) / 256, blk, 0, stream>>>(xk, cosb, sinb, k_t);
  transpose_v_kernel<<<(NKVH * HD * S_LEN) / 256, blk, 0, stream>>>(xv, v_t);

  // ---- attention ----
  gemm_bt<unsigned short><<<dim3(8, 8, NH), blk, 0, stream>>>(
      q_t, k_t, probs, S_LEN, S_LEN, HD,
      (long long)S_LEN * HD, (long long)S_LEN * HD, 4,
      (long long)S_LEN * S_LEN, S_LEN, inv_sqrt_hd);
  softmax_kernel<<<NH * S_LEN, blk, 0, stream>>>(probs);
  gemm_bt<unsigned short><<<dim3(1, 8, NH), blk, 0, stream>>>(
      probs, v_t, attn_bf, S_LEN, HD, S_LEN,
      (long long)S_LEN * S_LEN, (long long)HD * S_LEN, 4,
      (long long)HD, D_DIM, 1.f);

  // ---- output projection + residual ----
  lora_t_kernel<<<S_LEN, blk, 0, stream>>>(attn_bf, wo_a, t_o, D_DIM);
  gemm_bt<float><<<dim3(32, 8, 1), blk, 0, stream>>>(attn_bf, wo, attn_out, S_LEN, D_DIM, D_DIM, 0, 0, 1, 0, D_DIM, 1.f);
  rank_update_kernel<<<(S_LEN * D_DIM) / 256, blk, 0, stream>>>(attn_out, data2, t_o, wo_b, data, 2.f, (long long)S_LEN * D_DIM, D_DIM);

  // ---- FFN ----
  rmsnorm_kernel<<<S_LEN, blk, 0, stream>>>(data2, ffn_norm_w, f_bf, D_DIM);
  lora_t_kernel<<<S_LEN, blk, 0, stream>>>(f_bf, w1_a, t_1, D_DIM);
  lora_t_kernel<<<S_LEN, blk, 0, stream>>>(f_bf, w3_a, t_3, D_DIM);
  gemm_bt<float><<<dim3(112, 8, 1), blk, 0, stream>>>(f_bf, w1, gate, S_LEN, FF_DIM, D_DIM, 0, 0, 1, 0, FF_DIM, 1.f);
  gemm_bt<float><<<dim3(112, 8, 1), blk, 0, stream>>>(f_bf, w3, up, S_LEN, FF_DIM, D_DIM, 0, 0, 1, 0, FF_DIM, 1.f);
  rank_update_kernel<<<(S_LEN * FF_DIM) / 256, blk, 0, stream>>>(gate, gate, t_1, w1_b, nullptr, 2.f, (long long)S_LEN * FF_DIM, FF_DIM);
  rank_update_kernel<<<(S_LEN * FF_DIM) / 256, blk, 0, stream>>>(up, up, t_3, w3_b, nullptr, 2.f, (long long)S_LEN * FF_DIM, FF_DIM);
  silu_mul_kernel<<<(S_LEN * FF_DIM / 4) / 256, blk, 0, stream>>>(gate, up, gu_bf, (long long)S_LEN * FF_DIM / 4);
  lora_t_kernel<<<S_LEN, blk, 0, stream>>>(gu_bf, w2_a, t_2, FF_DIM);
  gemm_bt<float><<<dim3(32, 8, 1), blk, 0, stream>>>(gu_bf, w2, ffn, S_LEN, D_DIM, FF_DIM, 0, 0, 1, 0, D_DIM, 1.f);
  rank_update_kernel<<<(S_LEN * D_DIM) / 256, blk, 0, stream>>>(ffn, out, t_2, w2_b, data2, 2.f, (long long)S_LEN * D_DIM, D_DIM);
}